// Round 19
// baseline (753.075 us; speedup 1.0000x reference)
//
#include <hip/hip_runtime.h>
#include <hip/hip_bf16.h>

#define NTOT  65536
#define NE    524288
#define NG    64
#define NPG   1024
#define EMB   128
#define STEPS 4

typedef unsigned short u16;
typedef unsigned int   u32;
typedef __attribute__((ext_vector_type(8))) short          s16x8;
typedef __attribute__((ext_vector_type(8))) unsigned short us16x8;
typedef __attribute__((ext_vector_type(4))) float          f32x4;

__device__ __forceinline__ float lrelu(float v){ return v > 0.f ? v : 0.01f*v; }
__device__ __forceinline__ u16 f2bf(float f){
    u32 u = __float_as_uint(f);
    u32 r = (u + 0x7FFFu + ((u>>16)&1u)) >> 16;   // RNE
    return (u16)r;
}
__device__ __forceinline__ float bf2f(u16 u){ return __uint_as_float(((u32)u)<<16); }
__device__ __forceinline__ void store_out(u32* out, int j, float v){
    u32 b = (u32)f2bf(v);
    out[j] = (b << 16) | b;
}

// ================= CSR build =================
__global__ __launch_bounds__(256) void k_count(const int* __restrict__ dstv,
                                               u32* __restrict__ cnt){
    int e = blockIdx.x*256 + threadIdx.x;
    atomicAdd(&cnt[dstv[e]], 1u);
}

__global__ __launch_bounds__(1024) void k_scan(const u32* __restrict__ cnt,
                                               u32* __restrict__ off,
                                               u32* __restrict__ cursor){
    __shared__ u32 part[1024];
    int t = threadIdx.x;
    u32 s = 0;
    for (int i=0;i<64;i++) s += cnt[t*64+i];
    part[t] = s; __syncthreads();
    for (int d=1; d<1024; d<<=1){
        u32 v = (t>=d) ? part[t-d] : 0u;
        __syncthreads();
        part[t] += v;
        __syncthreads();
    }
    u32 base = (t==0) ? 0u : part[t-1];
    for (int i=0;i<64;i++){
        off[t*64+i] = base; cursor[t*64+i] = base;
        base += cnt[t*64+i];
    }
    if (t==1023) off[65536] = base;
}

__global__ __launch_bounds__(256) void k_scatter(const int* __restrict__ dstv,
                                                 u32* __restrict__ cursor,
                                                 u32* __restrict__ perm){
    int e = blockIdx.x*256 + threadIdx.x;
    u32 pos = atomicAdd(&cursor[dstv[e]], 1u);
    perm[pos] = e;
}

// ---------------- pre-gather: esrc[j]=srcv[perm[j]], eap[j]=ea[perm[j]] ----------------
__global__ __launch_bounds__(256) void k_gather(const u32* __restrict__ perm,
                        const int* __restrict__ srcv, const float* __restrict__ ea,
                        int* __restrict__ esrc, float* __restrict__ eap){
    int j = blockIdx.x*256 + threadIdx.x;
    u32 e = perm[j];
    esrc[j] = srcv[e];
    ((float4*)eap)[j] = ((const float4*)ea)[e];
}

// ---------------- weight convert+transpose to bf16: WT[col][k] ----------------
__global__ __launch_bounds__(256) void k_cvtw(const float* __restrict__ mW,
                        const float* __restrict__ aW, const float* __restrict__ fW,
                        u16* __restrict__ xwT, u16* __restrict__ waT,
                        u16* __restrict__ fwT){
    int idx = blockIdx.x*256 + threadIdx.x;     // 4 steps x 65536
    int step = idx >> 16;
    int r = idx & 65535;
    if (r < 16384){
        int c = r>>7, k = r&127;
        xwT[step*16384 + r] = f2bf(mW[(size_t)step*132*EMB + (size_t)k*EMB + c]);
    } else if (r < 49152){
        int j = r-16384; int c = j>>8, k = j&255;
        int k2 = (k<128) ? k : (k+128);         // skip xg rows [128,256)
        waT[step*32768 + j] = f2bf(aW[(size_t)step*384*EMB + (size_t)k2*EMB + c]);
    } else {
        int j = r-49152; int c = j>>7, k = j&127;
        fwT[step*16384 + j] = f2bf(fW[(size_t)step*EMB*EMB + (size_t)k*EMB + c]);
    }
}

// ---------------- embed: x(f32) + xb(bf16) ----------------
__global__ __launch_bounds__(256) void k_embed(const float* __restrict__ nf,
                        const float* __restrict__ W,
                        const float* __restrict__ b, float* __restrict__ x,
                        u16* __restrict__ xb) {
    int idx = blockIdx.x*256 + threadIdx.x;
    int n = idx >> 7, c = idx & 127;
    const float* f = nf + n*5;
    float acc = b[c];
    #pragma unroll
    for (int k=0;k<5;k++) acc += f[k]*W[k*EMB+c];
    float v = lrelu(acc);
    x[idx] = v;
    xb[idx] = f2bf(v);
}

// XCD swizzle for 1024-block kernels (64 nodes/block, 16 blocks/graph):
// graph g -> XCD g%8 so producer/consumer share an L2.
__device__ __forceinline__ int swz_n0_1024(int p){
    int xcd = p & 7, j = p >> 3;       // j in [0,128)
    int gi = j >> 4, wi = j & 15;
    int g = gi*8 + xcd;
    return (g*16 + wi)*64;
}

// ---------------- xw0 = xb @ mess_W0 + mb0 (MFMA, K=128) ----------------
__global__ __launch_bounds__(256) void k_xwm(const u16* __restrict__ xb,
                        const u16* __restrict__ WT, const float* __restrict__ b,
                        u16* __restrict__ xwo) {
    int t = threadIdx.x, wv = t>>6, lane = t&63;
    int n0 = swz_n0_1024(blockIdx.x);
    int row16 = lane&15, kg = lane>>4;
    f32x4 acc[8];
    #pragma unroll
    for (int ct=0;ct<8;ct++){
        float bc = b[ct*16+row16];
        acc[ct] = (f32x4){bc,bc,bc,bc};
    }
    for (int kt=0; kt<4; ++kt){
        s16x8 af = *(const s16x8*)(xb + (size_t)(n0+wv*16+row16)*EMB + kt*32 + kg*8);
        #pragma unroll
        for (int ct=0;ct<8;ct++){
            s16x8 bf = *(const s16x8*)(WT + (size_t)(ct*16+row16)*128 + kt*32 + kg*8);
            acc[ct] = __builtin_amdgcn_mfma_f32_16x16x32_bf16(af, bf, acc[ct], 0,0,0);
        }
    }
    #pragma unroll
    for (int ct=0;ct<8;ct++)
        #pragma unroll
        for (int reg=0;reg<4;reg++){
            int n = n0 + wv*16 + kg*4 + reg;
            xwo[(size_t)n*EMB + ct*16 + row16] = f2bf(acc[ct][reg]);
        }
}

// ---------------- gather-max (XCD-local, pre-gathered edges, 4-way ILP) ----------------
__global__ __launch_bounds__(256) void k_msgmax2(const u16* __restrict__ xwb,
                          const float* __restrict__ eap,
                          const int* __restrict__ esrc,
                          const u32* __restrict__ off,
                          const float* __restrict__ Wea,
                          u16* __restrict__ aggb) {
    int p = blockIdx.x;                 // 4096 blocks, 16 nodes each
    int xcd = p & 7, j = p >> 3;        // j in [0,512)
    int gi = j >> 6, wi = j & 63;
    int g = gi*8 + xcd;
    int t = threadIdx.x;
    int le = t>>4, c = (t&15)*8;
    int n = (g*64 + wi)*16 + le;
    float we[4][8];
    #pragma unroll
    for (int r=0;r<4;r++)
        #pragma unroll
        for (int q=0;q<8;q++) we[r][q] = Wea[r*EMB + c + q];
    u32 j0 = off[n], j1 = off[n+1];
    float racc[8];
    #pragma unroll
    for (int q=0;q<8;q++) racc[q] = -INFINITY;
    u32 jj = j0;
    for (; jj+4 <= j1; jj += 4){
        int s0 = esrc[jj], s1 = esrc[jj+1], s2 = esrc[jj+2], s3 = esrc[jj+3];
        const float4 ev0 = ((const float4*)eap)[jj];
        const float4 ev1 = ((const float4*)eap)[jj+1];
        const float4 ev2 = ((const float4*)eap)[jj+2];
        const float4 ev3 = ((const float4*)eap)[jj+3];
        us16x8 xv0 = *(const us16x8*)(xwb + (size_t)s0*EMB + c);
        us16x8 xv1 = *(const us16x8*)(xwb + (size_t)s1*EMB + c);
        us16x8 xv2 = *(const us16x8*)(xwb + (size_t)s2*EMB + c);
        us16x8 xv3 = *(const us16x8*)(xwb + (size_t)s3*EMB + c);
        #pragma unroll
        for (int q=0;q<8;q++){
            float m0 = bf2f(xv0[q])
                     + ev0.x*we[0][q] + ev0.y*we[1][q] + ev0.z*we[2][q] + ev0.w*we[3][q];
            float m1 = bf2f(xv1[q])
                     + ev1.x*we[0][q] + ev1.y*we[1][q] + ev1.z*we[2][q] + ev1.w*we[3][q];
            float m2 = bf2f(xv2[q])
                     + ev2.x*we[0][q] + ev2.y*we[1][q] + ev2.z*we[2][q] + ev2.w*we[3][q];
            float m3 = bf2f(xv3[q])
                     + ev3.x*we[0][q] + ev3.y*we[1][q] + ev3.z*we[2][q] + ev3.w*we[3][q];
            float ma = fmaxf(lrelu(m0), lrelu(m1));
            float mb = fmaxf(lrelu(m2), lrelu(m3));
            racc[q] = fmaxf(racc[q], fmaxf(ma, mb));
        }
    }
    for (; jj < j1; ++jj){
        int s0 = esrc[jj];
        const float4 ev0 = ((const float4*)eap)[jj];
        us16x8 xv0 = *(const us16x8*)(xwb + (size_t)s0*EMB + c);
        #pragma unroll
        for (int q=0;q<8;q++){
            float m0 = bf2f(xv0[q])
                     + ev0.x*we[0][q] + ev0.y*we[1][q] + ev0.z*we[2][q] + ev0.w*we[3][q];
            racc[q] = fmaxf(racc[q], lrelu(m0));
        }
    }
    u16* o = aggb + (size_t)n*EMB + c;
    #pragma unroll
    for (int q=0;q<8;q++) o[q] = f2bf((racc[q] == -INFINITY) ? 0.f : racc[q]);
}

// ---- GEMM1 (MFMA, K=256): x' = lrelu([xb|aggb]@WaT + xgw + b) + x ;
//      gate e=exp(x'.gw+gb) -> w[], denomp ----
__global__ __launch_bounds__(256) void k_gemm1(float* __restrict__ x,
                        u16* __restrict__ xb,
                        const u16* __restrict__ aggb, const u16* __restrict__ WT,
                        const float* __restrict__ b, const float* __restrict__ xgw,
                        const float* __restrict__ gw, const float* __restrict__ gb,
                        float* __restrict__ w, float* __restrict__ denomp) {
    __shared__ float gred[16];
    int t = threadIdx.x, wv = t>>6, lane = t&63;
    int n0 = swz_n0_1024(blockIdx.x);
    int g = n0>>10;
    int row16 = lane&15, kg = lane>>4;
    f32x4 acc[8];
    #pragma unroll
    for (int ct=0;ct<8;ct++){
        int cc = ct*16+row16;
        float bc = b[cc] + xgw[g*EMB + cc];
        acc[ct] = (f32x4){bc,bc,bc,bc};
    }
    for (int kt=0; kt<8; ++kt){
        const u16* ap = (kt<4)
            ? xb   + (size_t)(n0+wv*16+row16)*EMB + kt*32 + kg*8
            : aggb + (size_t)(n0+wv*16+row16)*EMB + (kt-4)*32 + kg*8;
        s16x8 af = *(const s16x8*)ap;
        #pragma unroll
        for (int ct=0;ct<8;ct++){
            s16x8 bf = *(const s16x8*)(WT + (size_t)(ct*16+row16)*256 + kt*32 + kg*8);
            acc[ct] = __builtin_amdgcn_mfma_f32_16x16x32_bf16(af, bf, acc[ct], 0,0,0);
        }
    }
    float gpart[4] = {0.f,0.f,0.f,0.f};
    #pragma unroll
    for (int ct=0;ct<8;ct++){
        int cc = ct*16 + row16;
        float gwc = gw[cc];
        #pragma unroll
        for (int reg=0;reg<4;reg++){
            int n = n0 + wv*16 + kg*4 + reg;
            float v = lrelu(acc[ct][reg]) + x[(size_t)n*EMB + cc];
            x[(size_t)n*EMB + cc] = v;
            xb[(size_t)n*EMB + cc] = f2bf(v);
            gpart[reg] += v*gwc;
        }
    }
    #pragma unroll
    for (int o=1;o<16;o<<=1)
        #pragma unroll
        for (int reg=0;reg<4;reg++) gpart[reg] += __shfl_xor(gpart[reg], o);
    if (row16 == 0){
        float es = 0.f;
        #pragma unroll
        for (int reg=0;reg<4;reg++){
            float e = expf(gpart[reg] + gb[0]);
            w[n0 + wv*16 + kg*4 + reg] = e;
            es += e;
        }
        gred[wv*4 + kg] = es;
    }
    __syncthreads();
    if (t==0){
        float s = 0.f;
        #pragma unroll
        for (int i=0;i<16;i++) s += gred[i];
        denomp[blockIdx.x] = s;
    }
}

// ---- feat (+ optional next-step xw), MFMA K=128 over xb ----
__global__ __launch_bounds__(256) void k_fx(const u16* __restrict__ xb,
                        const float* __restrict__ w,
                        const u16* __restrict__ fWT, const float* __restrict__ fb,
                        float* __restrict__ xgnp,
                        const u16* __restrict__ xWT, const float* __restrict__ mb,
                        u16* __restrict__ xwo) {
    __shared__ float red[4][128];
    int t = threadIdx.x, wv = t>>6, lane = t&63;
    int n0 = swz_n0_1024(blockIdx.x);
    int row16 = lane&15, kg = lane>>4;
    bool doxw = (xWT != nullptr);
    f32x4 accf[8], accx[8];
    #pragma unroll
    for (int ct=0;ct<8;ct++){
        int cc = ct*16+row16;
        float fc = fb[cc];
        accf[ct] = (f32x4){fc,fc,fc,fc};
        float mc = doxw ? mb[cc] : 0.f;
        accx[ct] = (f32x4){mc,mc,mc,mc};
    }
    for (int kt=0; kt<4; ++kt){
        s16x8 af = *(const s16x8*)(xb + (size_t)(n0+wv*16+row16)*EMB + kt*32 + kg*8);
        #pragma unroll
        for (int ct=0;ct<8;ct++){
            s16x8 bff = *(const s16x8*)(fWT + (size_t)(ct*16+row16)*128 + kt*32 + kg*8);
            accf[ct] = __builtin_amdgcn_mfma_f32_16x16x32_bf16(af, bff, accf[ct], 0,0,0);
        }
        if (doxw){
            #pragma unroll
            for (int ct=0;ct<8;ct++){
                s16x8 bfx = *(const s16x8*)(xWT + (size_t)(ct*16+row16)*128 + kt*32 + kg*8);
                accx[ct] = __builtin_amdgcn_mfma_f32_16x16x32_bf16(af, bfx, accx[ct], 0,0,0);
            }
        }
    }
    float e[4];
    #pragma unroll
    for (int reg=0;reg<4;reg++) e[reg] = w[n0 + wv*16 + kg*4 + reg];
    #pragma unroll
    for (int ct=0;ct<8;ct++){
        float p = 0.f;
        #pragma unroll
        for (int reg=0;reg<4;reg++){
            p += e[reg]*lrelu(accf[ct][reg]);
            if (doxw){
                int n = n0 + wv*16 + kg*4 + reg;
                xwo[(size_t)n*EMB + ct*16 + row16] = f2bf(accx[ct][reg]);
            }
        }
        p += __shfl_xor(p, 16);
        p += __shfl_xor(p, 32);
        if (kg == 0) red[wv][ct*16 + row16] = p;
    }
    __syncthreads();
    if (t < 128){
        float s = red[0][t]+red[1][t]+red[2][t]+red[3][t];
        xgnp[(size_t)blockIdx.x*128 + t] = s;
    }
}

// ---- xg update; partial sums indexed via inverse swizzle ----
__global__ __launch_bounds__(128) void k_tr(float* __restrict__ xg,
                     const float* __restrict__ xgnp, const float* __restrict__ denomp,
                     const float* __restrict__ W, const float* __restrict__ b,
                     const float* __restrict__ W2next, float* __restrict__ xgw) {
    __shared__ float in[256];
    __shared__ float xgs[128];
    int g = blockIdx.x, t = threadIdx.x;
    // blocks of graph g: p = (g&7) + 8*((g>>3)*16 + wi), wi in [0,16)
    float s = 0.f, d = 0.f;
    for (int wi=0; wi<16; wi++){
        int p = (g&7) + 8*((g>>3)*16 + wi);
        s += xgnp[(size_t)p*128 + t];
        d += denomp[p];
    }
    in[t]     = s/d;
    in[128+t] = xg[g*EMB + t];
    __syncthreads();
    float acc = b[t];
    for (int k=0;k<256;k++) acc += in[k]*W[(size_t)k*EMB + t];
    float xgnew = lrelu(acc) + in[128+t];
    xg[g*EMB+t] = xgnew;
    xgs[t] = xgnew;
    __syncthreads();
    if (W2next){
        float a2 = 0.f;
        for (int k=0;k<EMB;k++) a2 += xgs[k]*W2next[(size_t)k*EMB + t];
        xgw[g*EMB + t] = a2;
    }
}

// ---------------- graph heads ----------------
__global__ __launch_bounds__(64) void k_ghead(const float* __restrict__ xg,
                        const float* __restrict__ actW, const float* __restrict__ actb,
                        const float* __restrict__ valW, const float* __restrict__ valb,
                        u32* __restrict__ out) {
    int g = blockIdx.x, l = threadIdx.x;
    float xa = xg[g*EMB + l], xb = xg[g*EMB + 64 + l];
    float acc[6];
    #pragma unroll
    for (int o=0;o<5;o++) acc[o] = xa*actW[l*5+o] + xb*actW[(l+64)*5+o];
    acc[5] = xa*valW[l] + xb*valW[64+l];
    #pragma unroll
    for (int o=0;o<6;o++){
        float sv = acc[o];
        #pragma unroll
        for (int d=1;d<64;d<<=1) sv += __shfl_xor(sv, d);
        acc[o] = sv;
    }
    if (l==0){
        float lg[5], m = -1e30f;
        #pragma unroll
        for (int o=0;o<5;o++){ lg[o]=acc[o]+actb[o]; m = fmaxf(m, lg[o]); }
        float ssum=0.f;
        #pragma unroll
        for (int o=0;o<5;o++){ lg[o]=expf(lg[o]-m); ssum+=lg[o]; }
        float inv = 1.f/ssum;
        #pragma unroll
        for (int o=0;o<5;o++) store_out(out, g*5+o, lg[o]*inv);
        store_out(out, 328000 + g, acc[5] + valb[0]);
    }
}

// ---------------- node logits ----------------
__global__ __launch_bounds__(256) void k_nlog(const float* __restrict__ x,
                       const float* __restrict__ W,
                       const float* __restrict__ b, float* __restrict__ nl) {
    int n = blockIdx.x*256 + threadIdx.x;
    const float4* xr = (const float4*)(x + (size_t)n*EMB);
    float acc[5] = {b[0],b[1],b[2],b[3],b[4]};
    for (int k=0;k<32;k++){
        float4 v4 = xr[k];
        #pragma unroll
        for (int jj=0;jj<4;jj++){
            float v = (&v4.x)[jj];
            int k4 = k*4+jj;
            #pragma unroll
            for (int o=0;o<5;o++) acc[o] += v*W[k4*5+o];
        }
    }
    #pragma unroll
    for (int o=0;o<5;o++) nl[(size_t)n*5+o] = acc[o];
}

// ---------------- per-graph per-channel softmax over nodes ----------------
__global__ __launch_bounds__(256) void k_nodesm(const float* __restrict__ nl,
                         u32* __restrict__ out) {
    __shared__ float red[5][4];
    int g = blockIdx.x, t = threadIdx.x;
    float v[4][5];
    #pragma unroll
    for (int it=0; it<4; ++it){
        int n = g*NPG + it*256 + t;
        #pragma unroll
        for (int o=0;o<5;o++) v[it][o] = nl[(size_t)n*5+o];
    }
    float m[5];
    #pragma unroll
    for (int o=0;o<5;o++){
        float mm = fmaxf(fmaxf(v[0][o],v[1][o]),fmaxf(v[2][o],v[3][o]));
        #pragma unroll
        for (int d=1;d<64;d<<=1) mm = fmaxf(mm, __shfl_xor(mm,d));
        if ((t&63)==0) red[o][t>>6] = mm;
    }
    __syncthreads();
    #pragma unroll
    for (int o=0;o<5;o++)
        m[o] = fmaxf(fmaxf(red[o][0],red[o][1]),fmaxf(red[o][2],red[o][3]));
    __syncthreads();
    #pragma unroll
    for (int o=0;o<5;o++){
        float ss = 0.f;
        #pragma unroll
        for (int it=0;it<4;it++){ v[it][o] = expf(v[it][o]-m[o]); ss += v[it][o]; }
        #pragma unroll
        for (int d=1;d<64;d<<=1) ss += __shfl_xor(ss,d);
        if ((t&63)==0) red[o][t>>6] = ss;
    }
    __syncthreads();
    float s[5];
    #pragma unroll
    for (int o=0;o<5;o++)
        s[o] = 1.f/(red[o][0]+red[o][1]+red[o][2]+red[o][3]);
    #pragma unroll
    for (int it=0;it<4;it++){
        int n = g*NPG + it*256 + t;
        #pragma unroll
        for (int o=0;o<5;o++)
            store_out(out, 320 + n*5 + o, v[it][o]*s[o]);
    }
}

extern "C" void kernel_launch(void* const* d_in, const int* in_sizes, int n_in,
                              void* d_out, int out_size, void* d_ws, size_t ws_size,
                              hipStream_t stream) {
    const float* node_feats = (const float*)d_in[0];
    const float* edge_attr  = (const float*)d_in[1];
    const int*   edge_index = (const int*)d_in[2];
    const float* embed_W = (const float*)d_in[4];
    const float* embed_b = (const float*)d_in[5];
    const float* mess_W  = (const float*)d_in[6];
    const float* mess_b  = (const float*)d_in[7];
    const float* agg_W   = (const float*)d_in[8];
    const float* agg_b   = (const float*)d_in[9];
    const float* gate_W  = (const float*)d_in[10];
    const float* gate_b  = (const float*)d_in[11];
    const float* feat_W  = (const float*)d_in[12];
    const float* feat_b  = (const float*)d_in[13];
    const float* tr_W    = (const float*)d_in[14];
    const float* tr_b    = (const float*)d_in[15];
    const float* node_W  = (const float*)d_in[16];
    const float* node_b  = (const float*)d_in[17];
    const float* act_W   = (const float*)d_in[18];
    const float* act_b   = (const float*)d_in[19];
    const float* val_W   = (const float*)d_in[20];
    const float* val_b   = (const float*)d_in[21];

    // Workspace map (<=128MiB):
    //   x      f32 [0, 32M)          agg_bf/nl alias [32M,48M)   xb [48M,64M)
    //   CSR    64MiB: cnt | off(+1M) | cursor(+2M) | perm(+3M..+5M)
    //   70MiB: xgw 32K | denomp 4K | w 256K | xgnp 512K
    //   xwb    u16 [72MiB, 88MiB)
    //   88MiB: xwT 128K | waT 256K | fwT 128K
    //   esrc   int [96MiB, +2M) ; eap f32 [98MiB, +8M)
    char* ws = (char*)d_ws;
    float* x      = (float*)(ws);
    u16*   aggb   = (u16*)(ws + 33554432);
    float* nl     = (float*)(ws + 33554432);
    u16*   xb     = (u16*)(ws + 50331648);
    u32* cnt      = (u32*)(ws + 67108864);
    u32* off      = (u32*)(ws + 67108864 + 1048576);
    u32* cursor   = (u32*)(ws + 67108864 + 2097152);
    u32* perm     = (u32*)(ws + 67108864 + 3145728);
    float* xgw    = (float*)(ws + 73400320);
    float* denomp = (float*)(ws + 73400320 + 32768);
    float* w      = (float*)(ws + 73400320 + 65536);
    float* xgnp   = (float*)(ws + 73400320 + 327680);
    u16*   xwb    = (u16*)(ws + 75497472);
    u16*   xwT    = (u16*)(ws + 92274688);
    u16*   waT    = (u16*)(ws + 92274688 + 131072);
    u16*   fwT    = (u16*)(ws + 92274688 + 393216);
    int*   esrc   = (int*)(ws + 100663296);
    float* eap    = (float*)(ws + 102760448);
    u32* out = (u32*)d_out;
    float* xg     = (float*)((char*)d_out + 4096);

    const int* srcv = edge_index;
    const int* dstv = edge_index + NE;

    hipMemsetAsync(cnt, 0, NTOT*sizeof(u32), stream);
    k_count  <<<NE/256, 256, 0, stream>>>(dstv, cnt);
    k_scan   <<<1, 1024, 0, stream>>>(cnt, off, cursor);
    k_scatter<<<NE/256, 256, 0, stream>>>(dstv, cursor, perm);
    k_gather <<<NE/256, 256, 0, stream>>>(perm, srcv, edge_attr, esrc, eap);

    hipMemsetAsync(xg, 0, NG*EMB*sizeof(float), stream);
    hipMemsetAsync(xgw, 0, NG*EMB*sizeof(float), stream);
    k_cvtw<<<1024, 256, 0, stream>>>(mess_W, agg_W, feat_W, xwT, waT, fwT);
    k_embed<<<NTOT*EMB/256, 256, 0, stream>>>(node_feats, embed_W, embed_b, x, xb);
    k_xwm<<<NTOT/64, 256, 0, stream>>>(xb, xwT, mess_b, xwb);

    for (int i=0;i<STEPS;i++){
        bool last = (i+1 >= STEPS);
        k_msgmax2<<<NTOT/16, 256, 0, stream>>>(xwb, eap, esrc, off,
            mess_W + (size_t)i*132*EMB + (size_t)128*EMB, aggb);
        k_gemm1<<<NTOT/64, 256, 0, stream>>>(x, xb, aggb, waT + (size_t)i*32768,
            agg_b + i*EMB, xgw, gate_W + i*EMB, gate_b + i, w, denomp);
        k_fx<<<NTOT/64, 256, 0, stream>>>(xb, w, fwT + (size_t)i*16384,
            feat_b + i*EMB, xgnp,
            last ? nullptr : (xwT + (size_t)(i+1)*16384),
            last ? nullptr : (mess_b + (i+1)*EMB), xwb);
        k_tr<<<NG, 128, 0, stream>>>(xg, xgnp, denomp,
            tr_W + (size_t)i*256*EMB, tr_b + i*EMB,
            last ? nullptr : (agg_W + (size_t)(i+1)*384*EMB + (size_t)128*EMB), xgw);
    }

    k_ghead<<<NG, 64, 0, stream>>>(xg, act_W, act_b, val_W, val_b, out);
    k_nlog<<<NTOT/256, 256, 0, stream>>>(x, node_W, node_b, nl);
    k_nodesm<<<NG, 256, 0, stream>>>(nl, out);
}

// Round 20
// 713.880 us; speedup vs baseline: 1.0549x; 1.0549x over previous
//
#include <hip/hip_runtime.h>
#include <hip/hip_bf16.h>

#define NTOT  65536
#define NE    524288
#define NG    64
#define NPG   1024
#define EMB   128
#define STEPS 4

typedef unsigned short u16;
typedef unsigned int   u32;
typedef __attribute__((ext_vector_type(8))) short          s16x8;
typedef __attribute__((ext_vector_type(8))) unsigned short us16x8;
typedef __attribute__((ext_vector_type(4))) float          f32x4;

__device__ __forceinline__ float lrelu(float v){ return v > 0.f ? v : 0.01f*v; }
__device__ __forceinline__ u16 f2bf(float f){
    u32 u = __float_as_uint(f);
    u32 r = (u + 0x7FFFu + ((u>>16)&1u)) >> 16;   // RNE
    return (u16)r;
}
__device__ __forceinline__ float bf2f(u16 u){ return __uint_as_float(((u32)u)<<16); }
__device__ __forceinline__ void store_out(u32* out, int j, float v){
    u32 b = (u32)f2bf(v);
    out[j] = (b << 16) | b;
}

// ================= CSR build =================
__global__ __launch_bounds__(256) void k_count(const int* __restrict__ dstv,
                                               u32* __restrict__ cnt){
    int e = blockIdx.x*256 + threadIdx.x;
    atomicAdd(&cnt[dstv[e]], 1u);
}

__global__ __launch_bounds__(1024) void k_scan(const u32* __restrict__ cnt,
                                               u32* __restrict__ off,
                                               u32* __restrict__ cursor){
    __shared__ u32 part[1024];
    int t = threadIdx.x;
    u32 s = 0;
    for (int i=0;i<64;i++) s += cnt[t*64+i];
    part[t] = s; __syncthreads();
    for (int d=1; d<1024; d<<=1){
        u32 v = (t>=d) ? part[t-d] : 0u;
        __syncthreads();
        part[t] += v;
        __syncthreads();
    }
    u32 base = (t==0) ? 0u : part[t-1];
    for (int i=0;i<64;i++){
        off[t*64+i] = base; cursor[t*64+i] = base;
        base += cnt[t*64+i];
    }
    if (t==1023) off[65536] = base;
}

__global__ __launch_bounds__(256) void k_scatter(const int* __restrict__ dstv,
                                                 u32* __restrict__ cursor,
                                                 u32* __restrict__ perm){
    int e = blockIdx.x*256 + threadIdx.x;
    u32 pos = atomicAdd(&cursor[dstv[e]], 1u);
    perm[pos] = e;
}

// ---------------- pre-gather: esrc[j]=srcv[perm[j]], eap[j]=ea[perm[j]] ----------------
__global__ __launch_bounds__(256) void k_gather(const u32* __restrict__ perm,
                        const int* __restrict__ srcv, const float* __restrict__ ea,
                        int* __restrict__ esrc, float* __restrict__ eap){
    int j = blockIdx.x*256 + threadIdx.x;
    u32 e = perm[j];
    esrc[j] = srcv[e];
    ((float4*)eap)[j] = ((const float4*)ea)[e];
}

// ---------------- per-graph degree counting sort -> nperm ----------------
// Uniform-degree blocks for msgmax2 (kills lane divergence). Bin order within
// a degree is nondeterministic but numerics are per-node -> output bit-stable.
__global__ __launch_bounds__(256) void k_nsort(const u32* __restrict__ cnt,
                                               u32* __restrict__ nperm){
    __shared__ u32 hist[64];
    __shared__ u32 base[64];
    int g = blockIdx.x, t = threadIdx.x;
    if (t < 64) hist[t] = 0;
    __syncthreads();
    u32 deg[4];
    #pragma unroll
    for (int it=0; it<4; ++it){
        int i = it*256 + t;
        deg[it] = min(cnt[g*NPG + i], 63u);
        atomicAdd(&hist[deg[it]], 1u);
    }
    __syncthreads();
    if (t == 0){
        u32 s = 0;
        #pragma unroll
        for (int b2=0;b2<64;b2++){ base[b2] = s; s += hist[b2]; }
    }
    __syncthreads();
    #pragma unroll
    for (int it=0; it<4; ++it){
        int i = it*256 + t;
        u32 pos = atomicAdd(&base[deg[it]], 1u);
        nperm[g*NPG + pos] = g*NPG + i;
    }
}

// ---------------- weight convert+transpose to bf16: WT[col][k] ----------------
__global__ __launch_bounds__(256) void k_cvtw(const float* __restrict__ mW,
                        const float* __restrict__ aW, const float* __restrict__ fW,
                        u16* __restrict__ xwT, u16* __restrict__ waT,
                        u16* __restrict__ fwT){
    int idx = blockIdx.x*256 + threadIdx.x;     // 4 steps x 65536
    int step = idx >> 16;
    int r = idx & 65535;
    if (r < 16384){
        int c = r>>7, k = r&127;
        xwT[step*16384 + r] = f2bf(mW[(size_t)step*132*EMB + (size_t)k*EMB + c]);
    } else if (r < 49152){
        int j = r-16384; int c = j>>8, k = j&255;
        int k2 = (k<128) ? k : (k+128);         // skip xg rows [128,256)
        waT[step*32768 + j] = f2bf(aW[(size_t)step*384*EMB + (size_t)k2*EMB + c]);
    } else {
        int j = r-49152; int c = j>>7, k = j&127;
        fwT[step*16384 + j] = f2bf(fW[(size_t)step*EMB*EMB + (size_t)k*EMB + c]);
    }
}

// ---------------- embed: x(f32) + xb(bf16) ----------------
__global__ __launch_bounds__(256) void k_embed(const float* __restrict__ nf,
                        const float* __restrict__ W,
                        const float* __restrict__ b, float* __restrict__ x,
                        u16* __restrict__ xb) {
    int idx = blockIdx.x*256 + threadIdx.x;
    int n = idx >> 7, c = idx & 127;
    const float* f = nf + n*5;
    float acc = b[c];
    #pragma unroll
    for (int k=0;k<5;k++) acc += f[k]*W[k*EMB+c];
    float v = lrelu(acc);
    x[idx] = v;
    xb[idx] = f2bf(v);
}

// XCD swizzle for 1024-block kernels (64 nodes/block, 16 blocks/graph):
// graph g -> XCD g%8 so producer/consumer share an L2.
__device__ __forceinline__ int swz_n0_1024(int p){
    int xcd = p & 7, j = p >> 3;       // j in [0,128)
    int gi = j >> 4, wi = j & 15;
    int g = gi*8 + xcd;
    return (g*16 + wi)*64;
}

// ---------------- xw0 = xb @ mess_W0 + mb0 (MFMA, K=128) ----------------
__global__ __launch_bounds__(256) void k_xwm(const u16* __restrict__ xb,
                        const u16* __restrict__ WT, const float* __restrict__ b,
                        u16* __restrict__ xwo) {
    int t = threadIdx.x, wv = t>>6, lane = t&63;
    int n0 = swz_n0_1024(blockIdx.x);
    int row16 = lane&15, kg = lane>>4;
    f32x4 acc[8];
    #pragma unroll
    for (int ct=0;ct<8;ct++){
        float bc = b[ct*16+row16];
        acc[ct] = (f32x4){bc,bc,bc,bc};
    }
    for (int kt=0; kt<4; ++kt){
        s16x8 af = *(const s16x8*)(xb + (size_t)(n0+wv*16+row16)*EMB + kt*32 + kg*8);
        #pragma unroll
        for (int ct=0;ct<8;ct++){
            s16x8 bf = *(const s16x8*)(WT + (size_t)(ct*16+row16)*128 + kt*32 + kg*8);
            acc[ct] = __builtin_amdgcn_mfma_f32_16x16x32_bf16(af, bf, acc[ct], 0,0,0);
        }
    }
    #pragma unroll
    for (int ct=0;ct<8;ct++)
        #pragma unroll
        for (int reg=0;reg<4;reg++){
            int n = n0 + wv*16 + kg*4 + reg;
            xwo[(size_t)n*EMB + ct*16 + row16] = f2bf(acc[ct][reg]);
        }
}

// ---------------- gather-max (XCD-local, degree-bucketed, 4-way ILP) ----------------
__global__ __launch_bounds__(256) void k_msgmax2(const u16* __restrict__ xwb,
                          const float* __restrict__ eap,
                          const int* __restrict__ esrc,
                          const u32* __restrict__ off,
                          const u32* __restrict__ nperm,
                          const float* __restrict__ Wea,
                          u16* __restrict__ aggb) {
    int p = blockIdx.x;                 // 4096 blocks, 16 nodes each
    int xcd = p & 7, j = p >> 3;        // j in [0,512)
    int gi = j >> 6, wi = j & 63;
    int g = gi*8 + xcd;
    int t = threadIdx.x;
    int le = t>>4, c = (t&15)*8;
    int n = (int)nperm[(g*64 + wi)*16 + le];   // degree-bucketed assignment
    float we[4][8];
    #pragma unroll
    for (int r=0;r<4;r++)
        #pragma unroll
        for (int q=0;q<8;q++) we[r][q] = Wea[r*EMB + c + q];
    u32 j0 = off[n], j1 = off[n+1];
    float racc[8];
    #pragma unroll
    for (int q=0;q<8;q++) racc[q] = -INFINITY;
    u32 jj = j0;
    for (; jj+4 <= j1; jj += 4){
        int s0 = esrc[jj], s1 = esrc[jj+1], s2 = esrc[jj+2], s3 = esrc[jj+3];
        const float4 ev0 = ((const float4*)eap)[jj];
        const float4 ev1 = ((const float4*)eap)[jj+1];
        const float4 ev2 = ((const float4*)eap)[jj+2];
        const float4 ev3 = ((const float4*)eap)[jj+3];
        us16x8 xv0 = *(const us16x8*)(xwb + (size_t)s0*EMB + c);
        us16x8 xv1 = *(const us16x8*)(xwb + (size_t)s1*EMB + c);
        us16x8 xv2 = *(const us16x8*)(xwb + (size_t)s2*EMB + c);
        us16x8 xv3 = *(const us16x8*)(xwb + (size_t)s3*EMB + c);
        #pragma unroll
        for (int q=0;q<8;q++){
            float m0 = bf2f(xv0[q])
                     + ev0.x*we[0][q] + ev0.y*we[1][q] + ev0.z*we[2][q] + ev0.w*we[3][q];
            float m1 = bf2f(xv1[q])
                     + ev1.x*we[0][q] + ev1.y*we[1][q] + ev1.z*we[2][q] + ev1.w*we[3][q];
            float m2 = bf2f(xv2[q])
                     + ev2.x*we[0][q] + ev2.y*we[1][q] + ev2.z*we[2][q] + ev2.w*we[3][q];
            float m3 = bf2f(xv3[q])
                     + ev3.x*we[0][q] + ev3.y*we[1][q] + ev3.z*we[2][q] + ev3.w*we[3][q];
            float ma = fmaxf(lrelu(m0), lrelu(m1));
            float mb = fmaxf(lrelu(m2), lrelu(m3));
            racc[q] = fmaxf(racc[q], fmaxf(ma, mb));
        }
    }
    for (; jj < j1; ++jj){
        int s0 = esrc[jj];
        const float4 ev0 = ((const float4*)eap)[jj];
        us16x8 xv0 = *(const us16x8*)(xwb + (size_t)s0*EMB + c);
        #pragma unroll
        for (int q=0;q<8;q++){
            float m0 = bf2f(xv0[q])
                     + ev0.x*we[0][q] + ev0.y*we[1][q] + ev0.z*we[2][q] + ev0.w*we[3][q];
            racc[q] = fmaxf(racc[q], lrelu(m0));
        }
    }
    u16* o = aggb + (size_t)n*EMB + c;
    #pragma unroll
    for (int q=0;q<8;q++) o[q] = f2bf((racc[q] == -INFINITY) ? 0.f : racc[q]);
}

// ---- GEMM1 (MFMA, K=256): x' = lrelu([xb|aggb]@WaT + xgw + b) + x ;
//      gate e=exp(x'.gw+gb) -> w[], denomp ----
__global__ __launch_bounds__(256) void k_gemm1(float* __restrict__ x,
                        u16* __restrict__ xb,
                        const u16* __restrict__ aggb, const u16* __restrict__ WT,
                        const float* __restrict__ b, const float* __restrict__ xgw,
                        const float* __restrict__ gw, const float* __restrict__ gb,
                        float* __restrict__ w, float* __restrict__ denomp) {
    __shared__ float gred[16];
    int t = threadIdx.x, wv = t>>6, lane = t&63;
    int n0 = swz_n0_1024(blockIdx.x);
    int g = n0>>10;
    int row16 = lane&15, kg = lane>>4;
    f32x4 acc[8];
    #pragma unroll
    for (int ct=0;ct<8;ct++){
        int cc = ct*16+row16;
        float bc = b[cc] + xgw[g*EMB + cc];
        acc[ct] = (f32x4){bc,bc,bc,bc};
    }
    for (int kt=0; kt<8; ++kt){
        const u16* ap = (kt<4)
            ? xb   + (size_t)(n0+wv*16+row16)*EMB + kt*32 + kg*8
            : aggb + (size_t)(n0+wv*16+row16)*EMB + (kt-4)*32 + kg*8;
        s16x8 af = *(const s16x8*)ap;
        #pragma unroll
        for (int ct=0;ct<8;ct++){
            s16x8 bf = *(const s16x8*)(WT + (size_t)(ct*16+row16)*256 + kt*32 + kg*8);
            acc[ct] = __builtin_amdgcn_mfma_f32_16x16x32_bf16(af, bf, acc[ct], 0,0,0);
        }
    }
    float gpart[4] = {0.f,0.f,0.f,0.f};
    #pragma unroll
    for (int ct=0;ct<8;ct++){
        int cc = ct*16 + row16;
        float gwc = gw[cc];
        #pragma unroll
        for (int reg=0;reg<4;reg++){
            int n = n0 + wv*16 + kg*4 + reg;
            float v = lrelu(acc[ct][reg]) + x[(size_t)n*EMB + cc];
            x[(size_t)n*EMB + cc] = v;
            xb[(size_t)n*EMB + cc] = f2bf(v);
            gpart[reg] += v*gwc;
        }
    }
    #pragma unroll
    for (int o=1;o<16;o<<=1)
        #pragma unroll
        for (int reg=0;reg<4;reg++) gpart[reg] += __shfl_xor(gpart[reg], o);
    if (row16 == 0){
        float es = 0.f;
        #pragma unroll
        for (int reg=0;reg<4;reg++){
            float e = expf(gpart[reg] + gb[0]);
            w[n0 + wv*16 + kg*4 + reg] = e;
            es += e;
        }
        gred[wv*4 + kg] = es;
    }
    __syncthreads();
    if (t==0){
        float s = 0.f;
        #pragma unroll
        for (int i=0;i<16;i++) s += gred[i];
        denomp[blockIdx.x] = s;
    }
}

// ---- feat (+ optional next-step xw), MFMA K=128 over xb ----
__global__ __launch_bounds__(256) void k_fx(const u16* __restrict__ xb,
                        const float* __restrict__ w,
                        const u16* __restrict__ fWT, const float* __restrict__ fb,
                        float* __restrict__ xgnp,
                        const u16* __restrict__ xWT, const float* __restrict__ mb,
                        u16* __restrict__ xwo) {
    __shared__ float red[4][128];
    int t = threadIdx.x, wv = t>>6, lane = t&63;
    int n0 = swz_n0_1024(blockIdx.x);
    int row16 = lane&15, kg = lane>>4;
    bool doxw = (xWT != nullptr);
    f32x4 accf[8], accx[8];
    #pragma unroll
    for (int ct=0;ct<8;ct++){
        int cc = ct*16+row16;
        float fc = fb[cc];
        accf[ct] = (f32x4){fc,fc,fc,fc};
        float mc = doxw ? mb[cc] : 0.f;
        accx[ct] = (f32x4){mc,mc,mc,mc};
    }
    for (int kt=0; kt<4; ++kt){
        s16x8 af = *(const s16x8*)(xb + (size_t)(n0+wv*16+row16)*EMB + kt*32 + kg*8);
        #pragma unroll
        for (int ct=0;ct<8;ct++){
            s16x8 bff = *(const s16x8*)(fWT + (size_t)(ct*16+row16)*128 + kt*32 + kg*8);
            accf[ct] = __builtin_amdgcn_mfma_f32_16x16x32_bf16(af, bff, accf[ct], 0,0,0);
        }
        if (doxw){
            #pragma unroll
            for (int ct=0;ct<8;ct++){
                s16x8 bfx = *(const s16x8*)(xWT + (size_t)(ct*16+row16)*128 + kt*32 + kg*8);
                accx[ct] = __builtin_amdgcn_mfma_f32_16x16x32_bf16(af, bfx, accx[ct], 0,0,0);
            }
        }
    }
    float e[4];
    #pragma unroll
    for (int reg=0;reg<4;reg++) e[reg] = w[n0 + wv*16 + kg*4 + reg];
    #pragma unroll
    for (int ct=0;ct<8;ct++){
        float p = 0.f;
        #pragma unroll
        for (int reg=0;reg<4;reg++){
            p += e[reg]*lrelu(accf[ct][reg]);
            if (doxw){
                int n = n0 + wv*16 + kg*4 + reg;
                xwo[(size_t)n*EMB + ct*16 + row16] = f2bf(accx[ct][reg]);
            }
        }
        p += __shfl_xor(p, 16);
        p += __shfl_xor(p, 32);
        if (kg == 0) red[wv][ct*16 + row16] = p;
    }
    __syncthreads();
    if (t < 128){
        float s = red[0][t]+red[1][t]+red[2][t]+red[3][t];
        xgnp[(size_t)blockIdx.x*128 + t] = s;
    }
}

// ---- xg update; partial sums indexed via inverse swizzle ----
__global__ __launch_bounds__(128) void k_tr(float* __restrict__ xg,
                     const float* __restrict__ xgnp, const float* __restrict__ denomp,
                     const float* __restrict__ W, const float* __restrict__ b,
                     const float* __restrict__ W2next, float* __restrict__ xgw) {
    __shared__ float in[256];
    __shared__ float xgs[128];
    int g = blockIdx.x, t = threadIdx.x;
    // blocks of graph g: p = (g&7) + 8*((g>>3)*16 + wi), wi in [0,16)
    float s = 0.f, d = 0.f;
    for (int wi=0; wi<16; wi++){
        int p = (g&7) + 8*((g>>3)*16 + wi);
        s += xgnp[(size_t)p*128 + t];
        d += denomp[p];
    }
    in[t]     = s/d;
    in[128+t] = xg[g*EMB + t];
    __syncthreads();
    float acc = b[t];
    for (int k=0;k<256;k++) acc += in[k]*W[(size_t)k*EMB + t];
    float xgnew = lrelu(acc) + in[128+t];
    xg[g*EMB+t] = xgnew;
    xgs[t] = xgnew;
    __syncthreads();
    if (W2next){
        float a2 = 0.f;
        for (int k=0;k<EMB;k++) a2 += xgs[k]*W2next[(size_t)k*EMB + t];
        xgw[g*EMB + t] = a2;
    }
}

// ---------------- graph heads ----------------
__global__ __launch_bounds__(64) void k_ghead(const float* __restrict__ xg,
                        const float* __restrict__ actW, const float* __restrict__ actb,
                        const float* __restrict__ valW, const float* __restrict__ valb,
                        u32* __restrict__ out) {
    int g = blockIdx.x, l = threadIdx.x;
    float xa = xg[g*EMB + l], xb = xg[g*EMB + 64 + l];
    float acc[6];
    #pragma unroll
    for (int o=0;o<5;o++) acc[o] = xa*actW[l*5+o] + xb*actW[(l+64)*5+o];
    acc[5] = xa*valW[l] + xb*valW[64+l];
    #pragma unroll
    for (int o=0;o<6;o++){
        float sv = acc[o];
        #pragma unroll
        for (int d=1;d<64;d<<=1) sv += __shfl_xor(sv, d);
        acc[o] = sv;
    }
    if (l==0){
        float lg[5], m = -1e30f;
        #pragma unroll
        for (int o=0;o<5;o++){ lg[o]=acc[o]+actb[o]; m = fmaxf(m, lg[o]); }
        float ssum=0.f;
        #pragma unroll
        for (int o=0;o<5;o++){ lg[o]=expf(lg[o]-m); ssum+=lg[o]; }
        float inv = 1.f/ssum;
        #pragma unroll
        for (int o=0;o<5;o++) store_out(out, g*5+o, lg[o]*inv);
        store_out(out, 328000 + g, acc[5] + valb[0]);
    }
}

// ---------------- node logits ----------------
__global__ __launch_bounds__(256) void k_nlog(const float* __restrict__ x,
                       const float* __restrict__ W,
                       const float* __restrict__ b, float* __restrict__ nl) {
    int n = blockIdx.x*256 + threadIdx.x;
    const float4* xr = (const float4*)(x + (size_t)n*EMB);
    float acc[5] = {b[0],b[1],b[2],b[3],b[4]};
    for (int k=0;k<32;k++){
        float4 v4 = xr[k];
        #pragma unroll
        for (int jj=0;jj<4;jj++){
            float v = (&v4.x)[jj];
            int k4 = k*4+jj;
            #pragma unroll
            for (int o=0;o<5;o++) acc[o] += v*W[k4*5+o];
        }
    }
    #pragma unroll
    for (int o=0;o<5;o++) nl[(size_t)n*5+o] = acc[o];
}

// ---------------- per-graph per-channel softmax over nodes ----------------
__global__ __launch_bounds__(256) void k_nodesm(const float* __restrict__ nl,
                         u32* __restrict__ out) {
    __shared__ float red[5][4];
    int g = blockIdx.x, t = threadIdx.x;
    float v[4][5];
    #pragma unroll
    for (int it=0; it<4; ++it){
        int n = g*NPG + it*256 + t;
        #pragma unroll
        for (int o=0;o<5;o++) v[it][o] = nl[(size_t)n*5+o];
    }
    float m[5];
    #pragma unroll
    for (int o=0;o<5;o++){
        float mm = fmaxf(fmaxf(v[0][o],v[1][o]),fmaxf(v[2][o],v[3][o]));
        #pragma unroll
        for (int d=1;d<64;d<<=1) mm = fmaxf(mm, __shfl_xor(mm,d));
        if ((t&63)==0) red[o][t>>6] = mm;
    }
    __syncthreads();
    #pragma unroll
    for (int o=0;o<5;o++)
        m[o] = fmaxf(fmaxf(red[o][0],red[o][1]),fmaxf(red[o][2],red[o][3]));
    __syncthreads();
    #pragma unroll
    for (int o=0;o<5;o++){
        float ss = 0.f;
        #pragma unroll
        for (int it=0;it<4;it++){ v[it][o] = expf(v[it][o]-m[o]); ss += v[it][o]; }
        #pragma unroll
        for (int d=1;d<64;d<<=1) ss += __shfl_xor(ss,d);
        if ((t&63)==0) red[o][t>>6] = ss;
    }
    __syncthreads();
    float s[5];
    #pragma unroll
    for (int o=0;o<5;o++)
        s[o] = 1.f/(red[o][0]+red[o][1]+red[o][2]+red[o][3]);
    #pragma unroll
    for (int it=0;it<4;it++){
        int n = g*NPG + it*256 + t;
        #pragma unroll
        for (int o=0;o<5;o++)
            store_out(out, 320 + n*5 + o, v[it][o]*s[o]);
    }
}

extern "C" void kernel_launch(void* const* d_in, const int* in_sizes, int n_in,
                              void* d_out, int out_size, void* d_ws, size_t ws_size,
                              hipStream_t stream) {
    const float* node_feats = (const float*)d_in[0];
    const float* edge_attr  = (const float*)d_in[1];
    const int*   edge_index = (const int*)d_in[2];
    const float* embed_W = (const float*)d_in[4];
    const float* embed_b = (const float*)d_in[5];
    const float* mess_W  = (const float*)d_in[6];
    const float* mess_b  = (const float*)d_in[7];
    const float* agg_W   = (const float*)d_in[8];
    const float* agg_b   = (const float*)d_in[9];
    const float* gate_W  = (const float*)d_in[10];
    const float* gate_b  = (const float*)d_in[11];
    const float* feat_W  = (const float*)d_in[12];
    const float* feat_b  = (const float*)d_in[13];
    const float* tr_W    = (const float*)d_in[14];
    const float* tr_b    = (const float*)d_in[15];
    const float* node_W  = (const float*)d_in[16];
    const float* node_b  = (const float*)d_in[17];
    const float* act_W   = (const float*)d_in[18];
    const float* act_b   = (const float*)d_in[19];
    const float* val_W   = (const float*)d_in[20];
    const float* val_b   = (const float*)d_in[21];

    // Workspace map (<=128MiB):
    //   x      f32 [0, 32M)          agg_bf/nl alias [32M,48M)   xb [48M,64M)
    //   CSR    64MiB: cnt | off(+1M) | cursor(+2M) | perm(+3M..+5M)
    //   70MiB: xgw 32K | denomp 4K | w 256K | xgnp 512K
    //   xwb    u16 [72MiB, 88MiB)
    //   88MiB: xwT 128K | waT 256K | fwT 128K
    //   esrc   int [96MiB, +2M) ; eap f32 [98MiB, +8M) ; nperm [106MiB, +256K)
    char* ws = (char*)d_ws;
    float* x      = (float*)(ws);
    u16*   aggb   = (u16*)(ws + 33554432);
    float* nl     = (float*)(ws + 33554432);
    u16*   xb     = (u16*)(ws + 50331648);
    u32* cnt      = (u32*)(ws + 67108864);
    u32* off      = (u32*)(ws + 67108864 + 1048576);
    u32* cursor   = (u32*)(ws + 67108864 + 2097152);
    u32* perm     = (u32*)(ws + 67108864 + 3145728);
    float* xgw    = (float*)(ws + 73400320);
    float* denomp = (float*)(ws + 73400320 + 32768);
    float* w      = (float*)(ws + 73400320 + 65536);
    float* xgnp   = (float*)(ws + 73400320 + 327680);
    u16*   xwb    = (u16*)(ws + 75497472);
    u16*   xwT    = (u16*)(ws + 92274688);
    u16*   waT    = (u16*)(ws + 92274688 + 131072);
    u16*   fwT    = (u16*)(ws + 92274688 + 393216);
    int*   esrc   = (int*)(ws + 100663296);
    float* eap    = (float*)(ws + 102760448);
    u32*   nperm  = (u32*)(ws + 111149056);
    u32* out = (u32*)d_out;
    float* xg     = (float*)((char*)d_out + 4096);

    const int* srcv = edge_index;
    const int* dstv = edge_index + NE;

    hipMemsetAsync(cnt, 0, NTOT*sizeof(u32), stream);
    k_count  <<<NE/256, 256, 0, stream>>>(dstv, cnt);
    k_scan   <<<1, 1024, 0, stream>>>(cnt, off, cursor);
    k_scatter<<<NE/256, 256, 0, stream>>>(dstv, cursor, perm);
    k_gather <<<NE/256, 256, 0, stream>>>(perm, srcv, edge_attr, esrc, eap);
    k_nsort  <<<NG, 256, 0, stream>>>(cnt, nperm);

    hipMemsetAsync(xg, 0, NG*EMB*sizeof(float), stream);
    hipMemsetAsync(xgw, 0, NG*EMB*sizeof(float), stream);
    k_cvtw<<<1024, 256, 0, stream>>>(mess_W, agg_W, feat_W, xwT, waT, fwT);
    k_embed<<<NTOT*EMB/256, 256, 0, stream>>>(node_feats, embed_W, embed_b, x, xb);
    k_xwm<<<NTOT/64, 256, 0, stream>>>(xb, xwT, mess_b, xwb);

    for (int i=0;i<STEPS;i++){
        bool last = (i+1 >= STEPS);
        k_msgmax2<<<NTOT/16, 256, 0, stream>>>(xwb, eap, esrc, off, nperm,
            mess_W + (size_t)i*132*EMB + (size_t)128*EMB, aggb);
        k_gemm1<<<NTOT/64, 256, 0, stream>>>(x, xb, aggb, waT + (size_t)i*32768,
            agg_b + i*EMB, xgw, gate_W + i*EMB, gate_b + i, w, denomp);
        k_fx<<<NTOT/64, 256, 0, stream>>>(xb, w, fwT + (size_t)i*16384,
            feat_b + i*EMB, xgnp,
            last ? nullptr : (xwT + (size_t)(i+1)*16384),
            last ? nullptr : (mess_b + (i+1)*EMB), xwb);
        k_tr<<<NG, 128, 0, stream>>>(xg, xgnp, denomp,
            tr_W + (size_t)i*256*EMB, tr_b + i*EMB,
            last ? nullptr : (agg_W + (size_t)(i+1)*384*EMB + (size_t)128*EMB), xgw);
    }

    k_ghead<<<NG, 64, 0, stream>>>(xg, act_W, act_b, val_W, val_b, out);
    k_nlog<<<NTOT/256, 256, 0, stream>>>(x, node_W, node_b, nl);
    k_nodesm<<<NG, 256, 0, stream>>>(nl, out);
}

// Round 21
// 677.965 us; speedup vs baseline: 1.1108x; 1.0530x over previous
//
#include <hip/hip_runtime.h>
#include <hip/hip_bf16.h>

#define NTOT  65536
#define NE    524288
#define NG    64
#define NPG   1024
#define EMB   128
#define STEPS 4

typedef unsigned short u16;
typedef unsigned int   u32;
typedef __attribute__((ext_vector_type(8))) short          s16x8;
typedef __attribute__((ext_vector_type(8))) unsigned short us16x8;
typedef __attribute__((ext_vector_type(4))) float          f32x4;

__device__ __forceinline__ float lrelu(float v){ return v > 0.f ? v : 0.01f*v; }
__device__ __forceinline__ u16 f2bf(float f){
    u32 u = __float_as_uint(f);
    u32 r = (u + 0x7FFFu + ((u>>16)&1u)) >> 16;   // RNE
    return (u16)r;
}
__device__ __forceinline__ float bf2f(u16 u){ return __uint_as_float(((u32)u)<<16); }
__device__ __forceinline__ void store_out(u32* out, int j, float v){
    u32 b = (u32)f2bf(v);
    out[j] = (b << 16) | b;
}

// ================= CSR build =================
__global__ __launch_bounds__(256) void k_count(const int* __restrict__ dstv,
                                               u32* __restrict__ cnt){
    int e = blockIdx.x*256 + threadIdx.x;
    atomicAdd(&cnt[dstv[e]], 1u);
}

__global__ __launch_bounds__(1024) void k_scan(const u32* __restrict__ cnt,
                                               u32* __restrict__ off,
                                               u32* __restrict__ cursor){
    __shared__ u32 part[1024];
    int t = threadIdx.x;
    u32 s = 0;
    for (int i=0;i<64;i++) s += cnt[t*64+i];
    part[t] = s; __syncthreads();
    for (int d=1; d<1024; d<<=1){
        u32 v = (t>=d) ? part[t-d] : 0u;
        __syncthreads();
        part[t] += v;
        __syncthreads();
    }
    u32 base = (t==0) ? 0u : part[t-1];
    for (int i=0;i<64;i++){
        off[t*64+i] = base; cursor[t*64+i] = base;
        base += cnt[t*64+i];
    }
    if (t==1023) off[65536] = base;
}

__global__ __launch_bounds__(256) void k_scatter(const int* __restrict__ dstv,
                                                 u32* __restrict__ cursor,
                                                 u32* __restrict__ perm){
    int e = blockIdx.x*256 + threadIdx.x;
    u32 pos = atomicAdd(&cursor[dstv[e]], 1u);
    perm[pos] = e;
}

// ---------------- pre-gather: esrc[j]=srcv[perm[j]], eap[j]=ea[perm[j]] ----------------
__global__ __launch_bounds__(256) void k_gather(const u32* __restrict__ perm,
                        const int* __restrict__ srcv, const float* __restrict__ ea,
                        int* __restrict__ esrc, float* __restrict__ eap){
    int j = blockIdx.x*256 + threadIdx.x;
    u32 e = perm[j];
    esrc[j] = srcv[e];
    ((float4*)eap)[j] = ((const float4*)ea)[e];
}

// ---------------- per-graph degree counting sort -> nperm ----------------
__global__ __launch_bounds__(256) void k_nsort(const u32* __restrict__ cnt,
                                               u32* __restrict__ nperm){
    __shared__ u32 hist[64];
    __shared__ u32 base[64];
    int g = blockIdx.x, t = threadIdx.x;
    if (t < 64) hist[t] = 0;
    __syncthreads();
    u32 deg[4];
    #pragma unroll
    for (int it=0; it<4; ++it){
        int i = it*256 + t;
        deg[it] = min(cnt[g*NPG + i], 63u);
        atomicAdd(&hist[deg[it]], 1u);
    }
    __syncthreads();
    if (t == 0){
        u32 s = 0;
        #pragma unroll
        for (int b2=0;b2<64;b2++){ base[b2] = s; s += hist[b2]; }
    }
    __syncthreads();
    #pragma unroll
    for (int it=0; it<4; ++it){
        int i = it*256 + t;
        u32 pos = atomicAdd(&base[deg[it]], 1u);
        nperm[g*NPG + pos] = g*NPG + i;
    }
}

// ---------------- weight convert+transpose to bf16: WT[col][k] ----------------
__global__ __launch_bounds__(256) void k_cvtw(const float* __restrict__ mW,
                        const float* __restrict__ aW, const float* __restrict__ fW,
                        u16* __restrict__ xwT, u16* __restrict__ waT,
                        u16* __restrict__ fwT){
    int idx = blockIdx.x*256 + threadIdx.x;     // 4 steps x 65536
    int step = idx >> 16;
    int r = idx & 65535;
    if (r < 16384){
        int c = r>>7, k = r&127;
        xwT[step*16384 + r] = f2bf(mW[(size_t)step*132*EMB + (size_t)k*EMB + c]);
    } else if (r < 49152){
        int j = r-16384; int c = j>>8, k = j&255;
        int k2 = (k<128) ? k : (k+128);         // skip xg rows [128,256)
        waT[step*32768 + j] = f2bf(aW[(size_t)step*384*EMB + (size_t)k2*EMB + c]);
    } else {
        int j = r-49152; int c = j>>7, k = j&127;
        fwT[step*16384 + j] = f2bf(fW[(size_t)step*EMB*EMB + (size_t)k*EMB + c]);
    }
}

// ---------------- embed: xb(bf16) only ----------------
__global__ __launch_bounds__(256) void k_embed(const float* __restrict__ nf,
                        const float* __restrict__ W,
                        const float* __restrict__ b, u16* __restrict__ xb) {
    int idx = blockIdx.x*256 + threadIdx.x;
    int n = idx >> 7, c = idx & 127;
    const float* f = nf + n*5;
    float acc = b[c];
    #pragma unroll
    for (int k=0;k<5;k++) acc += f[k]*W[k*EMB+c];
    xb[idx] = f2bf(lrelu(acc));
}

// XCD swizzle for 1024-block kernels (64 nodes/block, 16 blocks/graph)
__device__ __forceinline__ int swz_n0_1024(int p){
    int xcd = p & 7, j = p >> 3;       // j in [0,128)
    int gi = j >> 4, wi = j & 15;
    int g = gi*8 + xcd;
    return (g*16 + wi)*64;
}

// ---------------- xw0 = xb @ mess_W0 + mb0 (MFMA, K=128) ----------------
__global__ __launch_bounds__(256) void k_xwm(const u16* __restrict__ xb,
                        const u16* __restrict__ WT, const float* __restrict__ b,
                        u16* __restrict__ xwo) {
    int t = threadIdx.x, wv = t>>6, lane = t&63;
    int n0 = swz_n0_1024(blockIdx.x);
    int row16 = lane&15, kg = lane>>4;
    f32x4 acc[8];
    #pragma unroll
    for (int ct=0;ct<8;ct++){
        float bc = b[ct*16+row16];
        acc[ct] = (f32x4){bc,bc,bc,bc};
    }
    for (int kt=0; kt<4; ++kt){
        s16x8 af = *(const s16x8*)(xb + (size_t)(n0+wv*16+row16)*EMB + kt*32 + kg*8);
        #pragma unroll
        for (int ct=0;ct<8;ct++){
            s16x8 bf = *(const s16x8*)(WT + (size_t)(ct*16+row16)*128 + kt*32 + kg*8);
            acc[ct] = __builtin_amdgcn_mfma_f32_16x16x32_bf16(af, bf, acc[ct], 0,0,0);
        }
    }
    #pragma unroll
    for (int ct=0;ct<8;ct++)
        #pragma unroll
        for (int reg=0;reg<4;reg++){
            int n = n0 + wv*16 + kg*4 + reg;
            xwo[(size_t)n*EMB + ct*16 + row16] = f2bf(acc[ct][reg]);
        }
}

// ---------------- gather-max (XCD-local, degree-bucketed, 4-way ILP) ----------------
__global__ __launch_bounds__(256) void k_msgmax2(const u16* __restrict__ xwb,
                          const float* __restrict__ eap,
                          const int* __restrict__ esrc,
                          const u32* __restrict__ off,
                          const u32* __restrict__ nperm,
                          const float* __restrict__ Wea,
                          u16* __restrict__ aggb) {
    int p = blockIdx.x;                 // 4096 blocks, 16 nodes each
    int xcd = p & 7, j = p >> 3;        // j in [0,512)
    int gi = j >> 6, wi = j & 63;
    int g = gi*8 + xcd;
    int t = threadIdx.x;
    int le = t>>4, c = (t&15)*8;
    int n = (int)nperm[(g*64 + wi)*16 + le];   // degree-bucketed assignment
    float we[4][8];
    #pragma unroll
    for (int r=0;r<4;r++)
        #pragma unroll
        for (int q=0;q<8;q++) we[r][q] = Wea[r*EMB + c + q];
    u32 j0 = off[n], j1 = off[n+1];
    float racc[8];
    #pragma unroll
    for (int q=0;q<8;q++) racc[q] = -INFINITY;
    u32 jj = j0;
    for (; jj+4 <= j1; jj += 4){
        int s0 = esrc[jj], s1 = esrc[jj+1], s2 = esrc[jj+2], s3 = esrc[jj+3];
        const float4 ev0 = ((const float4*)eap)[jj];
        const float4 ev1 = ((const float4*)eap)[jj+1];
        const float4 ev2 = ((const float4*)eap)[jj+2];
        const float4 ev3 = ((const float4*)eap)[jj+3];
        us16x8 xv0 = *(const us16x8*)(xwb + (size_t)s0*EMB + c);
        us16x8 xv1 = *(const us16x8*)(xwb + (size_t)s1*EMB + c);
        us16x8 xv2 = *(const us16x8*)(xwb + (size_t)s2*EMB + c);
        us16x8 xv3 = *(const us16x8*)(xwb + (size_t)s3*EMB + c);
        #pragma unroll
        for (int q=0;q<8;q++){
            float m0 = bf2f(xv0[q])
                     + ev0.x*we[0][q] + ev0.y*we[1][q] + ev0.z*we[2][q] + ev0.w*we[3][q];
            float m1 = bf2f(xv1[q])
                     + ev1.x*we[0][q] + ev1.y*we[1][q] + ev1.z*we[2][q] + ev1.w*we[3][q];
            float m2 = bf2f(xv2[q])
                     + ev2.x*we[0][q] + ev2.y*we[1][q] + ev2.z*we[2][q] + ev2.w*we[3][q];
            float m3 = bf2f(xv3[q])
                     + ev3.x*we[0][q] + ev3.y*we[1][q] + ev3.z*we[2][q] + ev3.w*we[3][q];
            float ma = fmaxf(lrelu(m0), lrelu(m1));
            float mb = fmaxf(lrelu(m2), lrelu(m3));
            racc[q] = fmaxf(racc[q], fmaxf(ma, mb));
        }
    }
    for (; jj < j1; ++jj){
        int s0 = esrc[jj];
        const float4 ev0 = ((const float4*)eap)[jj];
        us16x8 xv0 = *(const us16x8*)(xwb + (size_t)s0*EMB + c);
        #pragma unroll
        for (int q=0;q<8;q++){
            float m0 = bf2f(xv0[q])
                     + ev0.x*we[0][q] + ev0.y*we[1][q] + ev0.z*we[2][q] + ev0.w*we[3][q];
            racc[q] = fmaxf(racc[q], lrelu(m0));
        }
    }
    u16* o = aggb + (size_t)n*EMB + c;
    #pragma unroll
    for (int q=0;q<8;q++) o[q] = f2bf((racc[q] == -INFINITY) ? 0.f : racc[q]);
}

// ---- GEMM1 (MFMA, K=256): x' = lrelu([xb|aggb]@WaT + xgw + b) + xb ;
//      gate e=exp(x'.gw+gb) -> w[], denomp.  Residual chain lives in bf16. ----
__global__ __launch_bounds__(256) void k_gemm1(u16* __restrict__ xb,
                        const u16* __restrict__ aggb, const u16* __restrict__ WT,
                        const float* __restrict__ b, const float* __restrict__ xgw,
                        const float* __restrict__ gw, const float* __restrict__ gb,
                        float* __restrict__ w, float* __restrict__ denomp) {
    __shared__ float gred[16];
    int t = threadIdx.x, wv = t>>6, lane = t&63;
    int n0 = swz_n0_1024(blockIdx.x);
    int g = n0>>10;
    int row16 = lane&15, kg = lane>>4;
    f32x4 acc[8];
    #pragma unroll
    for (int ct=0;ct<8;ct++){
        int cc = ct*16+row16;
        float bc = b[cc] + xgw[g*EMB + cc];
        acc[ct] = (f32x4){bc,bc,bc,bc};
    }
    for (int kt=0; kt<8; ++kt){
        const u16* ap = (kt<4)
            ? xb   + (size_t)(n0+wv*16+row16)*EMB + kt*32 + kg*8
            : aggb + (size_t)(n0+wv*16+row16)*EMB + (kt-4)*32 + kg*8;
        s16x8 af = *(const s16x8*)ap;
        #pragma unroll
        for (int ct=0;ct<8;ct++){
            s16x8 bf = *(const s16x8*)(WT + (size_t)(ct*16+row16)*256 + kt*32 + kg*8);
            acc[ct] = __builtin_amdgcn_mfma_f32_16x16x32_bf16(af, bf, acc[ct], 0,0,0);
        }
    }
    float gpart[4] = {0.f,0.f,0.f,0.f};
    #pragma unroll
    for (int ct=0;ct<8;ct++){
        int cc = ct*16 + row16;
        float gwc = gw[cc];
        #pragma unroll
        for (int reg=0;reg<4;reg++){
            int n = n0 + wv*16 + kg*4 + reg;
            float v = lrelu(acc[ct][reg]) + bf2f(xb[(size_t)n*EMB + cc]);
            xb[(size_t)n*EMB + cc] = f2bf(v);
            gpart[reg] += v*gwc;
        }
    }
    #pragma unroll
    for (int o=1;o<16;o<<=1)
        #pragma unroll
        for (int reg=0;reg<4;reg++) gpart[reg] += __shfl_xor(gpart[reg], o);
    if (row16 == 0){
        float es = 0.f;
        #pragma unroll
        for (int reg=0;reg<4;reg++){
            float e = expf(gpart[reg] + gb[0]);
            w[n0 + wv*16 + kg*4 + reg] = e;
            es += e;
        }
        gred[wv*4 + kg] = es;
    }
    __syncthreads();
    if (t==0){
        float s = 0.f;
        #pragma unroll
        for (int i=0;i<16;i++) s += gred[i];
        denomp[blockIdx.x] = s;
    }
}

// ---- feat (+ optional next-step xw), MFMA K=128 over xb ----
__global__ __launch_bounds__(256) void k_fx(const u16* __restrict__ xb,
                        const float* __restrict__ w,
                        const u16* __restrict__ fWT, const float* __restrict__ fb,
                        float* __restrict__ xgnp,
                        const u16* __restrict__ xWT, const float* __restrict__ mb,
                        u16* __restrict__ xwo) {
    __shared__ float red[4][128];
    int t = threadIdx.x, wv = t>>6, lane = t&63;
    int n0 = swz_n0_1024(blockIdx.x);
    int row16 = lane&15, kg = lane>>4;
    bool doxw = (xWT != nullptr);
    f32x4 accf[8], accx[8];
    #pragma unroll
    for (int ct=0;ct<8;ct++){
        int cc = ct*16+row16;
        float fc = fb[cc];
        accf[ct] = (f32x4){fc,fc,fc,fc};
        float mc = doxw ? mb[cc] : 0.f;
        accx[ct] = (f32x4){mc,mc,mc,mc};
    }
    for (int kt=0; kt<4; ++kt){
        s16x8 af = *(const s16x8*)(xb + (size_t)(n0+wv*16+row16)*EMB + kt*32 + kg*8);
        #pragma unroll
        for (int ct=0;ct<8;ct++){
            s16x8 bff = *(const s16x8*)(fWT + (size_t)(ct*16+row16)*128 + kt*32 + kg*8);
            accf[ct] = __builtin_amdgcn_mfma_f32_16x16x32_bf16(af, bff, accf[ct], 0,0,0);
        }
        if (doxw){
            #pragma unroll
            for (int ct=0;ct<8;ct++){
                s16x8 bfx = *(const s16x8*)(xWT + (size_t)(ct*16+row16)*128 + kt*32 + kg*8);
                accx[ct] = __builtin_amdgcn_mfma_f32_16x16x32_bf16(af, bfx, accx[ct], 0,0,0);
            }
        }
    }
    float e[4];
    #pragma unroll
    for (int reg=0;reg<4;reg++) e[reg] = w[n0 + wv*16 + kg*4 + reg];
    #pragma unroll
    for (int ct=0;ct<8;ct++){
        float p = 0.f;
        #pragma unroll
        for (int reg=0;reg<4;reg++){
            p += e[reg]*lrelu(accf[ct][reg]);
            if (doxw){
                int n = n0 + wv*16 + kg*4 + reg;
                xwo[(size_t)n*EMB + ct*16 + row16] = f2bf(accx[ct][reg]);
            }
        }
        p += __shfl_xor(p, 16);
        p += __shfl_xor(p, 32);
        if (kg == 0) red[wv][ct*16 + row16] = p;
    }
    __syncthreads();
    if (t < 128){
        float s = red[0][t]+red[1][t]+red[2][t]+red[3][t];
        xgnp[(size_t)blockIdx.x*128 + t] = s;
    }
}

// ---- xg update; partial sums indexed via inverse swizzle ----
__global__ __launch_bounds__(128) void k_tr(float* __restrict__ xg,
                     const float* __restrict__ xgnp, const float* __restrict__ denomp,
                     const float* __restrict__ W, const float* __restrict__ b,
                     const float* __restrict__ W2next, float* __restrict__ xgw) {
    __shared__ float in[256];
    __shared__ float xgs[128];
    int g = blockIdx.x, t = threadIdx.x;
    float s = 0.f, d = 0.f;
    for (int wi=0; wi<16; wi++){
        int p = (g&7) + 8*((g>>3)*16 + wi);
        s += xgnp[(size_t)p*128 + t];
        d += denomp[p];
    }
    in[t]     = s/d;
    in[128+t] = xg[g*EMB + t];
    __syncthreads();
    float acc = b[t];
    for (int k=0;k<256;k++) acc += in[k]*W[(size_t)k*EMB + t];
    float xgnew = lrelu(acc) + in[128+t];
    xg[g*EMB+t] = xgnew;
    xgs[t] = xgnew;
    __syncthreads();
    if (W2next){
        float a2 = 0.f;
        for (int k=0;k<EMB;k++) a2 += xgs[k]*W2next[(size_t)k*EMB + t];
        xgw[g*EMB + t] = a2;
    }
}

// ---------------- graph heads ----------------
__global__ __launch_bounds__(64) void k_ghead(const float* __restrict__ xg,
                        const float* __restrict__ actW, const float* __restrict__ actb,
                        const float* __restrict__ valW, const float* __restrict__ valb,
                        u32* __restrict__ out) {
    int g = blockIdx.x, l = threadIdx.x;
    float xa = xg[g*EMB + l], xb = xg[g*EMB + 64 + l];
    float acc[6];
    #pragma unroll
    for (int o=0;o<5;o++) acc[o] = xa*actW[l*5+o] + xb*actW[(l+64)*5+o];
    acc[5] = xa*valW[l] + xb*valW[64+l];
    #pragma unroll
    for (int o=0;o<6;o++){
        float sv = acc[o];
        #pragma unroll
        for (int d=1;d<64;d<<=1) sv += __shfl_xor(sv, d);
        acc[o] = sv;
    }
    if (l==0){
        float lg[5], m = -1e30f;
        #pragma unroll
        for (int o=0;o<5;o++){ lg[o]=acc[o]+actb[o]; m = fmaxf(m, lg[o]); }
        float ssum=0.f;
        #pragma unroll
        for (int o=0;o<5;o++){ lg[o]=expf(lg[o]-m); ssum+=lg[o]; }
        float inv = 1.f/ssum;
        #pragma unroll
        for (int o=0;o<5;o++) store_out(out, g*5+o, lg[o]*inv);
        store_out(out, 328000 + g, acc[5] + valb[0]);
    }
}

// ---------------- node logits (reads bf16 xb) ----------------
__global__ __launch_bounds__(256) void k_nlog(const u16* __restrict__ xb,
                       const float* __restrict__ W,
                       const float* __restrict__ b, float* __restrict__ nl) {
    int n = blockIdx.x*256 + threadIdx.x;
    const u16* xr = xb + (size_t)n*EMB;
    float acc[5] = {b[0],b[1],b[2],b[3],b[4]};
    for (int k8=0;k8<16;k8++){
        us16x8 v8 = *(const us16x8*)(xr + k8*8);
        #pragma unroll
        for (int jj=0;jj<8;jj++){
            float v = bf2f(v8[jj]);
            int k = k8*8+jj;
            #pragma unroll
            for (int o=0;o<5;o++) acc[o] += v*W[k*5+o];
        }
    }
    #pragma unroll
    for (int o=0;o<5;o++) nl[(size_t)n*5+o] = acc[o];
}

// ---------------- per-graph per-channel softmax over nodes ----------------
__global__ __launch_bounds__(256) void k_nodesm(const float* __restrict__ nl,
                         u32* __restrict__ out) {
    __shared__ float red[5][4];
    int g = blockIdx.x, t = threadIdx.x;
    float v[4][5];
    #pragma unroll
    for (int it=0; it<4; ++it){
        int n = g*NPG + it*256 + t;
        #pragma unroll
        for (int o=0;o<5;o++) v[it][o] = nl[(size_t)n*5+o];
    }
    float m[5];
    #pragma unroll
    for (int o=0;o<5;o++){
        float mm = fmaxf(fmaxf(v[0][o],v[1][o]),fmaxf(v[2][o],v[3][o]));
        #pragma unroll
        for (int d=1;d<64;d<<=1) mm = fmaxf(mm, __shfl_xor(mm,d));
        if ((t&63)==0) red[o][t>>6] = mm;
    }
    __syncthreads();
    #pragma unroll
    for (int o=0;o<5;o++)
        m[o] = fmaxf(fmaxf(red[o][0],red[o][1]),fmaxf(red[o][2],red[o][3]));
    __syncthreads();
    #pragma unroll
    for (int o=0;o<5;o++){
        float ss = 0.f;
        #pragma unroll
        for (int it=0;it<4;it++){ v[it][o] = expf(v[it][o]-m[o]); ss += v[it][o]; }
        #pragma unroll
        for (int d=1;d<64;d<<=1) ss += __shfl_xor(ss,d);
        if ((t&63)==0) red[o][t>>6] = ss;
    }
    __syncthreads();
    float s[5];
    #pragma unroll
    for (int o=0;o<5;o++)
        s[o] = 1.f/(red[o][0]+red[o][1]+red[o][2]+red[o][3]);
    #pragma unroll
    for (int it=0;it<4;it++){
        int n = g*NPG + it*256 + t;
        #pragma unroll
        for (int o=0;o<5;o++)
            store_out(out, 320 + n*5 + o, v[it][o]*s[o]);
    }
}

extern "C" void kernel_launch(void* const* d_in, const int* in_sizes, int n_in,
                              void* d_out, int out_size, void* d_ws, size_t ws_size,
                              hipStream_t stream) {
    const float* node_feats = (const float*)d_in[0];
    const float* edge_attr  = (const float*)d_in[1];
    const int*   edge_index = (const int*)d_in[2];
    const float* embed_W = (const float*)d_in[4];
    const float* embed_b = (const float*)d_in[5];
    const float* mess_W  = (const float*)d_in[6];
    const float* mess_b  = (const float*)d_in[7];
    const float* agg_W   = (const float*)d_in[8];
    const float* agg_b   = (const float*)d_in[9];
    const float* gate_W  = (const float*)d_in[10];
    const float* gate_b  = (const float*)d_in[11];
    const float* feat_W  = (const float*)d_in[12];
    const float* feat_b  = (const float*)d_in[13];
    const float* tr_W    = (const float*)d_in[14];
    const float* tr_b    = (const float*)d_in[15];
    const float* node_W  = (const float*)d_in[16];
    const float* node_b  = (const float*)d_in[17];
    const float* act_W   = (const float*)d_in[18];
    const float* act_b   = (const float*)d_in[19];
    const float* val_W   = (const float*)d_in[20];
    const float* val_b   = (const float*)d_in[21];

    // Workspace map (<=128MiB): f32 x ELIMINATED (bf16 residual chain in xb).
    //   agg_bf/nl alias [32M,48M)   xb [48M,64M)
    //   CSR    64MiB: cnt | off(+1M) | cursor(+2M) | perm(+3M..+5M)
    //   70MiB: xgw 32K | denomp 4K | w 256K | xgnp 512K
    //   xwb    u16 [72MiB, 88MiB)
    //   88MiB: xwT 128K | waT 256K | fwT 128K
    //   esrc   int [96MiB, +2M) ; eap f32 [98MiB, +8M) ; nperm [106MiB, +256K)
    char* ws = (char*)d_ws;
    u16*   aggb   = (u16*)(ws + 33554432);
    float* nl     = (float*)(ws + 33554432);
    u16*   xb     = (u16*)(ws + 50331648);
    u32* cnt      = (u32*)(ws + 67108864);
    u32* off      = (u32*)(ws + 67108864 + 1048576);
    u32* cursor   = (u32*)(ws + 67108864 + 2097152);
    u32* perm     = (u32*)(ws + 67108864 + 3145728);
    float* xgw    = (float*)(ws + 73400320);
    float* denomp = (float*)(ws + 73400320 + 32768);
    float* w      = (float*)(ws + 73400320 + 65536);
    float* xgnp   = (float*)(ws + 73400320 + 327680);
    u16*   xwb    = (u16*)(ws + 75497472);
    u16*   xwT    = (u16*)(ws + 92274688);
    u16*   waT    = (u16*)(ws + 92274688 + 131072);
    u16*   fwT    = (u16*)(ws + 92274688 + 393216);
    int*   esrc   = (int*)(ws + 100663296);
    float* eap    = (float*)(ws + 102760448);
    u32*   nperm  = (u32*)(ws + 111149056);
    u32* out = (u32*)d_out;
    float* xg     = (float*)((char*)d_out + 4096);

    const int* srcv = edge_index;
    const int* dstv = edge_index + NE;

    hipMemsetAsync(cnt, 0, NTOT*sizeof(u32), stream);
    k_count  <<<NE/256, 256, 0, stream>>>(dstv, cnt);
    k_scan   <<<1, 1024, 0, stream>>>(cnt, off, cursor);
    k_scatter<<<NE/256, 256, 0, stream>>>(dstv, cursor, perm);
    k_gather <<<NE/256, 256, 0, stream>>>(perm, srcv, edge_attr, esrc, eap);
    k_nsort  <<<NG, 256, 0, stream>>>(cnt, nperm);

    hipMemsetAsync(xg, 0, NG*EMB*sizeof(float), stream);
    hipMemsetAsync(xgw, 0, NG*EMB*sizeof(float), stream);
    k_cvtw<<<1024, 256, 0, stream>>>(mess_W, agg_W, feat_W, xwT, waT, fwT);
    k_embed<<<NTOT*EMB/256, 256, 0, stream>>>(node_feats, embed_W, embed_b, xb);
    k_xwm<<<NTOT/64, 256, 0, stream>>>(xb, xwT, mess_b, xwb);

    for (int i=0;i<STEPS;i++){
        bool last = (i+1 >= STEPS);
        k_msgmax2<<<NTOT/16, 256, 0, stream>>>(xwb, eap, esrc, off, nperm,
            mess_W + (size_t)i*132*EMB + (size_t)128*EMB, aggb);
        k_gemm1<<<NTOT/64, 256, 0, stream>>>(xb, aggb, waT + (size_t)i*32768,
            agg_b + i*EMB, xgw, gate_W + i*EMB, gate_b + i, w, denomp);
        k_fx<<<NTOT/64, 256, 0, stream>>>(xb, w, fwT + (size_t)i*16384,
            feat_b + i*EMB, xgnp,
            last ? nullptr : (xwT + (size_t)(i+1)*16384),
            last ? nullptr : (mess_b + (i+1)*EMB), xwb);
        k_tr<<<NG, 128, 0, stream>>>(xg, xgnp, denomp,
            tr_W + (size_t)i*256*EMB, tr_b + i*EMB,
            last ? nullptr : (agg_W + (size_t)(i+1)*384*EMB + (size_t)128*EMB), xgw);
    }

    k_ghead<<<NG, 64, 0, stream>>>(xg, act_W, act_b, val_W, val_b, out);
    k_nlog<<<NTOT/256, 256, 0, stream>>>(xb, node_W, node_b, nl);
    k_nodesm<<<NG, 256, 0, stream>>>(nl, out);
}